// Round 15
// baseline (188.262 us; speedup 1.0000x reference)
//
#include <hip/hip_runtime.h>
#include <math.h>

#define B_  2
#define S_  2048
#define D_  1024
#define H_  16
#define HD_ 64
#define BS_ (B_ * S_)   // 4096 rows

typedef __bf16 bf16_t;
typedef __bf16 bf16x8 __attribute__((ext_vector_type(8)));
typedef __bf16 bf16x4 __attribute__((ext_vector_type(4)));
typedef float  f32x4  __attribute__((ext_vector_type(4)));
typedef short  s16x4  __attribute__((ext_vector_type(4)));

#define QSCALE 0.18033688011112042f   // 0.125 * log2(e)
#define FREQC  0.28782313662425575f   // ln(10000)/32

// Async global->LDS DMA, 16 B per lane (wave-uniform LDS base + lane*16).
__device__ __forceinline__ void async_ld16(const bf16_t* g, bf16_t* l)
{
    __builtin_amdgcn_global_load_lds(
        (const __attribute__((address_space(1))) void*)g,
        (__attribute__((address_space(3))) void*)l,
        16, 0, 0);
}

// pack 4 f32 -> bf16x4 (packed-convert instruction when available)
__device__ __forceinline__ s16x4 pack_bf16x4(float a, float b, float c, float d)
{
#if __has_builtin(__builtin_amdgcn_cvt_pk_bf16_f32)
    typedef __bf16 bf16x2_t __attribute__((ext_vector_type(2)));
    bf16x2_t lo = __builtin_amdgcn_cvt_pk_bf16_f32(a, b);
    bf16x2_t hi = __builtin_amdgcn_cvt_pk_bf16_f32(c, d);
    union { struct { bf16x2_t l, h; } p; s16x4 sv; } u;
    u.p.l = lo; u.p.h = hi;
    return u.sv;
#else
    union { bf16x4 hv; s16x4 sv; } u;
    u.hv[0] = (bf16_t)a; u.hv[1] = (bf16_t)b;
    u.hv[2] = (bf16_t)c; u.hv[3] = (bf16_t)d;
    return u.sv;
#endif
}

// chunk-slot base per 64-row q-tile t (chunks of 8 k-tiles; 80 slots/(b,h))
__device__ __forceinline__ int chunk_base(int t)
{
    if (t < 8)  return t;
    if (t < 16) return 8 + 2 * (t - 8);
    if (t < 24) return 24 + 3 * (t - 16);
    return 48 + 4 * (t - 24);
}

// ---------------------------------------------------------------------------
// Merged: LayerNorm (blocks 0..4095) + weight fp32->bf16 convert (4096..8191).
// ---------------------------------------------------------------------------
__global__ __launch_bounds__(256) void ln_cvt(const float* __restrict__ x,
                                              const float* __restrict__ gamma,
                                              const float* __restrict__ beta,
                                              bf16_t* __restrict__ y,
                                              const float* __restrict__ wa,
                                              const float* __restrict__ wb,
                                              bf16_t* __restrict__ oa,
                                              bf16_t* __restrict__ ob)
{
    if (blockIdx.x >= BS_) {
        int idx = (blockIdx.x - BS_) * 256 + threadIdx.x;
        const int NA = 3 * D_ * D_ / 4;
        if (idx < NA) {
            float4 v = ((const float4*)wa)[idx];
            bf16x4 p;
            p[0] = (bf16_t)v.x; p[1] = (bf16_t)v.y; p[2] = (bf16_t)v.z; p[3] = (bf16_t)v.w;
            ((bf16x4*)oa)[idx] = p;
        } else {
            int j = idx - NA;
            float4 v = ((const float4*)wb)[j];
            bf16x4 p;
            p[0] = (bf16_t)v.x; p[1] = (bf16_t)v.y; p[2] = (bf16_t)v.z; p[3] = (bf16_t)v.w;
            ((bf16x4*)ob)[j] = p;
        }
        return;
    }
    int row = blockIdx.x;
    float4 v = ((const float4*)(x + (size_t)row * D_))[threadIdx.x];
    float sum = v.x + v.y + v.z + v.w;
    float sq  = v.x * v.x + v.y * v.y + v.z * v.z + v.w * v.w;
#pragma unroll
    for (int off = 32; off > 0; off >>= 1) {
        sum += __shfl_down(sum, off);
        sq  += __shfl_down(sq, off);
    }
    __shared__ float s_sum[4], s_sq[4];
    int wave = threadIdx.x >> 6;
    if ((threadIdx.x & 63) == 0) { s_sum[wave] = sum; s_sq[wave] = sq; }
    __syncthreads();
    float tsum = s_sum[0] + s_sum[1] + s_sum[2] + s_sum[3];
    float tsq  = s_sq[0] + s_sq[1] + s_sq[2] + s_sq[3];
    float mean = tsum * (1.0f / D_);
    float var  = tsq * (1.0f / D_) - mean * mean;
    float rstd = rsqrtf(var + 1e-5f);
    float4 g = ((const float4*)gamma)[threadIdx.x];
    float4 b = ((const float4*)beta)[threadIdx.x];
    bf16x4 o;
    o[0] = (bf16_t)((v.x - mean) * rstd * g.x + b.x);
    o[1] = (bf16_t)((v.y - mean) * rstd * g.y + b.y);
    o[2] = (bf16_t)((v.z - mean) * rstd * g.z + b.z);
    o[3] = (bf16_t)((v.w - mean) * rstd * g.w + b.w);
    *(bf16x4*)&y[(size_t)row * D_ + threadIdx.x * 4] = o;
}

// ---------------------------------------------------------------------------
// bf16 MFMA GEMM: C = A[M][K] * W[N][K]^T + bias. (unchanged from round 14)
// ---------------------------------------------------------------------------
template<int MODE, int TM>
__global__ __launch_bounds__(256) void gemm_bf16(const bf16_t* __restrict__ A,
                                                 const bf16_t* __restrict__ W,
                                                 const float* __restrict__ bias,
                                                 float* __restrict__ outf,
                                                 bf16_t* __restrict__ qout,
                                                 bf16_t* __restrict__ kout,
                                                 bf16_t* __restrict__ vout,
                                                 int M, int N, int K)
{
    constexpr int ASZ = TM * 32;
    constexpr int BUF = ASZ + 4096;
    constexpr int SMEM = (MODE == 1) ? 18432 : 2 * BUF;
    constexpr int MI = (TM == 128) ? 4 : 2;
    __shared__ bf16_t smem[SMEM];
    const int bm = blockIdx.y * TM, bn = blockIdx.x * 128;
    const int tid = threadIdx.x;
    const int wave = tid >> 6, lane = tid & 63;
    const int ln16 = lane & 15, quad = lane >> 4;
    const int wr = (wave >> 1) * (TM / 2), wc = (wave & 1) * 64;
    const int slot_a = (quad ^ (ln16 & 3)) * 8;

    f32x4 acc[MI][4];
#pragma unroll
    for (int i = 0; i < MI; i++)
#pragma unroll
        for (int j = 0; j < 4; j++) acc[i][j] = (f32x4){0.f, 0.f, 0.f, 0.f};

#pragma unroll
    for (int j = 0; j < TM / 64; j++) {
        int e = j * 256 + tid;
        int r = e >> 2, cg = ((e & 3) ^ (r & 3)) * 8;
        async_ld16(&A[(size_t)(bm + r) * K + cg], smem + e * 8);
    }
#pragma unroll
    for (int j = 0; j < 2; j++) {
        int e = j * 256 + tid;
        int r = e >> 2, cg = ((e & 3) ^ (r & 3)) * 8;
        async_ld16(&W[(size_t)(bn + r) * K + cg], smem + ASZ + e * 8);
    }
    __syncthreads();

    for (int k0 = 0, it = 0; k0 < K; k0 += 32, it++) {
        const bf16_t* cur = smem + (it & 1) * BUF;
        bf16_t* nxt = smem + ((it & 1) ^ 1) * BUF;
        if (k0 + 32 < K) {
#pragma unroll
            for (int j = 0; j < TM / 64; j++) {
                int e = j * 256 + tid;
                int r = e >> 2, cg = ((e & 3) ^ (r & 3)) * 8;
                async_ld16(&A[(size_t)(bm + r) * K + k0 + 32 + cg], nxt + e * 8);
            }
#pragma unroll
            for (int j = 0; j < 2; j++) {
                int e = j * 256 + tid;
                int r = e >> 2, cg = ((e & 3) ^ (r & 3)) * 8;
                async_ld16(&W[(size_t)(bn + r) * K + k0 + 32 + cg], nxt + ASZ + e * 8);
            }
        }

        bf16x8 af[MI], bf[4];
#pragma unroll
        for (int mi = 0; mi < MI; mi++)
            af[mi] = *(const bf16x8*)&cur[(wr + mi * 16 + ln16) * 32 + slot_a];
#pragma unroll
        for (int ni = 0; ni < 4; ni++)
            bf[ni] = *(const bf16x8*)&cur[ASZ + (wc + ni * 16 + ln16) * 32 + slot_a];
#pragma unroll
        for (int mi = 0; mi < MI; mi++)
#pragma unroll
            for (int ni = 0; ni < 4; ni++)
                acc[mi][ni] = __builtin_amdgcn_mfma_f32_16x16x32_bf16(
                    af[mi], bf[ni], acc[mi][ni], 0, 0, 0);

        __syncthreads();
    }

#pragma unroll
    for (int ni = 0; ni < 4; ni++) {
        float bb = bias[bn + wc + ni * 16 + ln16];
#pragma unroll
        for (int mi = 0; mi < MI; mi++)
#pragma unroll
            for (int r = 0; r < 4; r++) acc[mi][ni][r] += bb;
    }

    if (MODE == 0) {
#pragma unroll
        for (int ni = 0; ni < 4; ni++) {
            int n = bn + wc + ni * 16 + ln16;
#pragma unroll
            for (int mi = 0; mi < MI; mi++)
#pragma unroll
                for (int r = 0; r < 4; r++)
                    outf[(size_t)(bm + wr + mi * 16 + quad * 4 + r) * N + n] = acc[mi][ni][r];
        }
    } else {
        const int n64 = (bn + wc) >> 6;
        const int t = n64 % 3, h = n64 / 3;
        bf16_t* T = smem + wave * (64 * 72);   // per-wave strip; safe after loop
        if (t == 2) {
#pragma unroll
            for (int mi = 0; mi < 4; mi++) {
#pragma unroll
                for (int ni = 0; ni < 4; ni++) {
                    bf16x4 pk;
#pragma unroll
                    for (int r = 0; r < 4; r++) pk[r] = (bf16_t)acc[mi][ni][r];
                    *(bf16x4*)&T[(ni * 16 + ln16) * 72 + mi * 16 + quad * 4] = pk;
                }
            }
            int m0 = bm + wr;
            int bi = m0 >> 11, s0g = m0 & (S_ - 1);
#pragma unroll
            for (int e = lane; e < 512; e += 64) {
                int hd_l = e >> 3, c8 = (e & 7) << 3;
                *(bf16x8*)&vout[((size_t)(bi * H_ + h) * HD_ + hd_l) * S_ + s0g + c8] =
                    *(const bf16x8*)&T[hd_l * 72 + c8];
            }
        } else {
            float fr0 = __expf(-(float)ln16 * FREQC);
            float fr1 = __expf(-(float)(16 + ln16) * FREQC);
            float sc = (t == 0) ? QSCALE : 1.0f;
#pragma unroll
            for (int mi = 0; mi < 4; mi++) {
#pragma unroll
                for (int r = 0; r < 4; r++) {
                    int m = bm + wr + mi * 16 + quad * 4 + r;
                    float s = (float)(m & (S_ - 1));
                    float sn0, cs0, sn1, cs1;
                    __sincosf(s * fr0, &sn0, &cs0);
                    __sincosf(s * fr1, &sn1, &cs1);
                    int rowo = (mi * 16 + quad * 4 + r) * 72;
                    float x1 = acc[mi][0][r], x2 = acc[mi][2][r];
                    T[rowo + ln16]      = (bf16_t)((x1 * cs0 - x2 * sn0) * sc);
                    T[rowo + 32 + ln16] = (bf16_t)((x2 * cs0 + x1 * sn0) * sc);
                    x1 = acc[mi][1][r]; x2 = acc[mi][3][r];
                    T[rowo + 16 + ln16] = (bf16_t)((x1 * cs1 - x2 * sn1) * sc);
                    T[rowo + 48 + ln16] = (bf16_t)((x2 * cs1 + x1 * sn1) * sc);
                }
            }
            bf16_t* dst = (t == 0) ? qout : kout;
#pragma unroll
            for (int e = lane; e < 512; e += 64) {
                int row_l = e >> 3, c8 = (e & 7) << 3;
                int m = bm + wr + row_l;
                int b = m >> 11, s = m & (S_ - 1);
                *(bf16x8*)&dst[((size_t)(b * H_ + h) * S_ + s) * HD_ + c8] =
                    *(const bf16x8*)&T[row_l * 72 + c8];
            }
        }
    }
}

// ---------------------------------------------------------------------------
// Flash attention pass 1 (round-14 structure + 3 VALU cuts):
// 512 threads / 8 waves on a 128-row q-supertile, chunks of 8 k-tiles,
// DMA double-buffer, 1 barrier/iter, no-max softmax.
//  - l accumulated by MFMA (ones-vector A-frag): removes 16 VALU adds/iter.
//  - waves skip iterations entirely past their diagonal (all-masked = zero).
//  - packed f32->bf16 converts (cvt_pk) when available.
// ---------------------------------------------------------------------------
__global__ __launch_bounds__(512) void attn_p1(const bf16_t* __restrict__ q_buf,
                                               const bf16_t* __restrict__ k_buf,
                                               const bf16_t* __restrict__ v_t,
                                               bf16_t* __restrict__ part_o,
                                               float* __restrict__ part_l)
{
    __shared__ bf16_t KS[2][4096];
    __shared__ bf16_t VS[2][4096];

    const int h = blockIdx.y, b = blockIdx.z;
    const int xx = 39 - blockIdx.x;   // heavy (8-tile) chunks first
    int T, c;
    if (xx < 4)       { T = xx;                 c = 0; }
    else if (xx < 12) { int y = xx - 4;  T = 4 + (y >> 1); c = y & 1; }
    else if (xx < 24) { int y = xx - 12; int q = y / 3; T = 8 + q; c = y - 3 * q; }
    else              { int y = xx - 24; T = 12 + (y >> 2); c = y & 3; }
    const int k0c = c * 8;
    const int k1c = min(2 * T + 1, k0c + 7);

    const int tid = threadIdx.x;
    const int wave = tid >> 6, lane = tid & 63;
    const int ln16 = lane & 15, quad = lane >> 4;
    const int w0 = T * 128 + wave * 16;
    const int dt = w0 >> 6;            // this wave's diagonal k-tile
    const int s7 = ln16 & 7;

    const bf16_t* qb = q_buf + (size_t)(b * H_ + h) * S_ * HD_;
    const bf16_t* kb = k_buf + (size_t)(b * H_ + h) * S_ * HD_;
    const bf16_t* vb = v_t  + (size_t)(b * H_ + h) * HD_ * S_;

    // staging geometry: thread handles one 8-elem chunk of K and of V
    const int r0 = tid >> 3, c0 = ((tid & 7) ^ (r0 & 7)) * 8;

    bf16x8 qf[2];
#pragma unroll
    for (int kc = 0; kc < 2; kc++)
        qf[kc] = *(const bf16x8*)&qb[(size_t)(w0 + ln16) * HD_ + kc * 32 + quad * 8];

    f32x4 o[4];
#pragma unroll
    for (int mi = 0; mi < 4; mi++) o[mi] = (f32x4){0.f, 0.f, 0.f, 0.f};
    f32x4 ol = (f32x4){0.f, 0.f, 0.f, 0.f};   // l accumulator (via MFMA)

    // all-ones A-fragment (bf16 1.0 = 0x3F80) for the l MFMA
    union { bf16x4 hv; s16x4 sv; } ones_u;
    ones_u.hv[0] = (bf16_t)1.0f; ones_u.hv[1] = (bf16_t)1.0f;
    ones_u.hv[2] = (bf16_t)1.0f; ones_u.hv[3] = (bf16_t)1.0f;
    const s16x4 ones = ones_u.sv;

    // prologue: DMA tile k0c into buffer 0
    async_ld16(&kb[(size_t)(k0c * 64 + r0) * HD_ + c0], &KS[0][tid * 8]);
    async_ld16(&vb[(size_t)r0 * S_ + k0c * 64 + c0], &VS[0][tid * 8]);
    __syncthreads();

    for (int kt = k0c; kt <= k1c; kt++) {
        const int cb = (kt - k0c) & 1;
        if (kt < k1c) {   // DMA next tile; lands during this iter's compute
            const int nb = cb ^ 1, kn = kt + 1;
            async_ld16(&kb[(size_t)(kn * 64 + r0) * HD_ + c0], &KS[nb][tid * 8]);
            async_ld16(&vb[(size_t)r0 * S_ + kn * 64 + c0], &VS[nb][tid * 8]);
        }

        if (kt <= dt) {   // wave-uniform: skip all-masked (zero) iterations
            const bf16_t* Kc = &KS[cb][0];
            const bf16_t* Vc = &VS[cb][0];

            f32x4 st[4];
#pragma unroll
            for (int cbx = 0; cbx < 4; cbx++) st[cbx] = (f32x4){0.f, 0.f, 0.f, 0.f};
#pragma unroll
            for (int kc = 0; kc < 2; kc++)
#pragma unroll
                for (int cbx = 0; cbx < 4; cbx++) {
                    bf16x8 kf = *(const bf16x8*)&Kc[(cbx * 16 + ln16) * 64 + ((kc * 4 + quad) ^ s7) * 8];
                    st[cbx] = __builtin_amdgcn_mfma_f32_16x16x32_bf16(kf, qf[kc], st[cbx], 0, 0, 0);
                }

            if (kt == dt) {   // causal mask on the diagonal tile only
                int q_g = w0 + ln16;
#pragma unroll
                for (int cbx = 0; cbx < 4; cbx++) {
                    int key0 = kt * 64 + cbx * 16 + quad * 4;
#pragma unroll
                    for (int r = 0; r < 4; r++)
                        if (key0 + r > q_g) st[cbx][r] = -1e30f;
                }
            }

            // no-max softmax: p = exp2(s), packed to bf16
            s16x4 pf4[4];
#pragma unroll
            for (int cbx = 0; cbx < 4; cbx++) {
                float p0 = exp2f(st[cbx][0]);
                float p1 = exp2f(st[cbx][1]);
                float p2 = exp2f(st[cbx][2]);
                float p3 = exp2f(st[cbx][3]);
                pf4[cbx] = pack_bf16x4(p0, p1, p2, p3);
            }

            // O^T += V^T P^T ; l += 1^T P^T (extra MFMA, rows all equal l)
#pragma unroll
            for (int cbx = 0; cbx < 4; cbx++) {
                int slot = ((cbx * 2 + (quad >> 1)) ^ s7) * 8 + (quad & 1) * 4;
#pragma unroll
                for (int mi = 0; mi < 4; mi++) {
                    union { bf16x4 hv; s16x4 sv; } uv;
                    uv.hv = *(const bf16x4*)&Vc[(mi * 16 + ln16) * 64 + slot];
                    o[mi] = __builtin_amdgcn_mfma_f32_16x16x16bf16_1k(uv.sv, pf4[cbx], o[mi], 0, 0, 0);
                }
                ol = __builtin_amdgcn_mfma_f32_16x16x16bf16_1k(ones, pf4[cbx], ol, 0, 0, 0);
            }
        }

        __syncthreads();   // publishes next tile; all waves done reading cur
    }

    // write partial: slot of 64-row tile t = dt, chunk c
    const size_t pidx = (size_t)(b * H_ + h) * 80 + chunk_base(dt) + c;
    bf16_t* po = part_o + pidx * 4096;
    const int q_l = (wave & 3) * 16 + ln16;
#pragma unroll
    for (int mi = 0; mi < 4; mi++) {
        bf16x4 pk;
#pragma unroll
        for (int r = 0; r < 4; r++) pk[r] = (bf16_t)o[mi][r];
        *(bf16x4*)&po[q_l * 64 + mi * 16 + quad * 4] = pk;
    }
    if (quad == 0)
        part_l[pidx * 64 + q_l] = ol[0];   // all rows of the l-MFMA equal l[q]
}

// ---------------------------------------------------------------------------
// Flash attention pass 2: plain-sum combine of <=4 absolute-scale partials.
// Grid (32,16,2); thread -> (q_l = tid>>2, 16 hd elems).
// ---------------------------------------------------------------------------
__global__ __launch_bounds__(256) void attn_p2(const bf16_t* __restrict__ part_o,
                                               const float* __restrict__ part_l,
                                               bf16_t* __restrict__ ctx)
{
    const int t = blockIdx.x, h = blockIdx.y, b = blockIdx.z;
    const int nch = (t >> 3) + 1;
    const size_t p0 = (size_t)(b * H_ + h) * 80 + chunk_base(t);
    const int q_l = threadIdx.x >> 2;
    const int hg = (threadIdx.x & 3) * 16;

    float L = 0.f;
    float f0[8] = {0,0,0,0,0,0,0,0}, f1[8] = {0,0,0,0,0,0,0,0};
#pragma unroll
    for (int i = 0; i < 4; i++) {
        if (i < nch) {
            L += part_l[(p0 + i) * 64 + q_l];
            const bf16_t* oi = part_o + (p0 + i) * 4096 + q_l * 64 + hg;
            bf16x8 v0 = *(const bf16x8*)oi;
            bf16x8 v1 = *(const bf16x8*)(oi + 8);
#pragma unroll
            for (int j = 0; j < 8; j++) {
                f0[j] += (float)v0[j];
                f1[j] += (float)v1[j];
            }
        }
    }
    float invL = 1.0f / L;
    bf16x8 out0, out1;
#pragma unroll
    for (int j = 0; j < 8; j++) {
        out0[j] = (bf16_t)(f0[j] * invL);
        out1[j] = (bf16_t)(f1[j] * invL);
    }
    bf16_t* dst = &ctx[(size_t)(b * S_ + t * 64 + q_l) * D_ + h * HD_ + hg];
    *(bf16x8*)dst = out0;
    *(bf16x8*)(dst + 8) = out1;
}

// ---------------------------------------------------------------------------
extern "C" void kernel_launch(void* const* d_in, const int* in_sizes, int n_in,
                              void* d_out, int out_size, void* d_ws, size_t ws_size,
                              hipStream_t stream)
{
    const float* hidden = (const float*)d_in[0];
    const float* gamma  = (const float*)d_in[1];
    const float* beta   = (const float*)d_in[2];
    const float* qkv_w  = (const float*)d_in[3];
    const float* qkv_b  = (const float*)d_in[4];
    const float* proj_w = (const float*)d_in[5];
    const float* proj_b = (const float*)d_in[6];
    float* out = (float*)d_out;

    char* ws = (char*)d_ws;
    const size_t MB = 1024 * 1024;
    bf16_t* x_ln = (bf16_t*)(ws);             //  0.. 8 MB
    bf16_t* wq   = (bf16_t*)(ws +  8 * MB);   //  8..14 MB
    bf16_t* wp   = (bf16_t*)(ws + 14 * MB);   // 14..16 MB
    bf16_t* qbf  = (bf16_t*)(ws + 16 * MB);   // 16..24 MB
    bf16_t* kbf  = (bf16_t*)(ws + 24 * MB);   // 24..32 MB
    bf16_t* vtb  = (bf16_t*)(ws + 32 * MB);   // 32..40 MB
    bf16_t* ctx  = (bf16_t*)(ws + 40 * MB);   // 40..48 MB
    bf16_t* po   = (bf16_t*)(ws + 48 * MB);   // 48..68 MB (2560 x 8 KB)
    float*  pl   = (float*)(ws + 68 * MB);    // 68..68.7 MB (2560 x 256 B)

    ln_cvt<<<BS_ + 4096, 256, 0, stream>>>(hidden, gamma, beta, x_ln,
                                           qkv_w, proj_w, wq, wp);
    gemm_bf16<1, 128><<<dim3(24, 32), 256, 0, stream>>>(
        x_ln, wq, qkv_b, nullptr, qbf, kbf, vtb, BS_, 3 * D_, D_);
    attn_p1<<<dim3(40, H_, B_), 512, 0, stream>>>(qbf, kbf, vtb, po, pl);
    attn_p2<<<dim3(32, H_, B_), 256, 0, stream>>>(po, pl, ctx);
    gemm_bf16<0, 64><<<dim3(8, 64), 256, 0, stream>>>(
        ctx, wp, proj_b, out, nullptr, nullptr, nullptr, BS_, D_, D_);
}